// Round 1
// baseline (14919.554 us; speedup 1.0000x reference)
//
#include <hip/hip_runtime.h>
#include <cstdint>
#include <cstddef>

#define HID 512
#define N_INT 131072
#define N_INIT 32768

// ---------------------------------------------------------------------------
// Layer 0 (2 -> 512). Tangent of layer0 pre-act is just a row of W0, second
// tangent is 0, so everything is closed-form elementwise.
// streams (interior): 0=h, 1=t_dot(e_t), 2=t_ddot(e_t), 3=t_dot(e_x), 4=t_ddot(e_x)
// ---------------------------------------------------------------------------
__global__ __launch_bounds__(512) void layer0_int_kernel(
    const float* __restrict__ xt, long row0, int rows,
    const float* __restrict__ W0, const float* __restrict__ b0,
    float* __restrict__ act, size_t sstride)
{
  long i = blockIdx.x;
  if (i >= rows) return;
  int j = threadIdx.x;
  float x = xt[(row0 + i) * 2 + 0];
  float t = xt[(row0 + i) * 2 + 1];
  float wx = W0[j];          // W0[0][j]  (e_x direction)
  float wt = W0[HID + j];    // W0[1][j]  (e_t direction)
  float a = fmaf(x, wx, fmaf(t, wt, b0[j]));
  float y = tanhf(a);
  float d = 1.f - y * y;
  size_t o = (size_t)i * HID + j;
  act[o]               = y;
  act[sstride + o]     = d * wt;                 // ydot  (e_t)
  act[2 * sstride + o] = -2.f * y * d * wt * wt; // yddot (e_t), a_dd = 0
  act[3 * sstride + o] = d * wx;                 // ydot  (e_x)
  act[4 * sstride + o] = -2.f * y * d * wx * wx; // yddot (e_x)
}

// init pass: streams 0=h, 1=t_dot(e_t)
__global__ __launch_bounds__(512) void layer0_init_kernel(
    const float* __restrict__ xt, long row0, int rows,
    const float* __restrict__ W0, const float* __restrict__ b0,
    float* __restrict__ act, size_t sstride)
{
  long i = blockIdx.x;
  if (i >= rows) return;
  int j = threadIdx.x;
  float x = xt[(row0 + i) * 2 + 0];
  float t = xt[(row0 + i) * 2 + 1];
  float wx = W0[j];
  float wt = W0[HID + j];
  float a = fmaf(x, wx, fmaf(t, wt, b0[j]));
  float y = tanhf(a);
  float d = 1.f - y * y;
  size_t o = (size_t)i * HID + j;
  act[o]           = y;
  act[sstride + o] = d * wt;
}

// ---------------------------------------------------------------------------
// Fused hidden-layer GEMM: for NS streams sharing W (512x512),
//   A_s = In_s @ W   (bias only enters primal stream in the epilogue)
// then tanh-coupling epilogue writes the NS output streams.
// Tile 64(M-points) x 64(N), K-step 16, 256 threads, 4x4 micro-tile per stream.
// ---------------------------------------------------------------------------
template <int NS>
__global__ __launch_bounds__(256) void gemm_fused(
    const float* __restrict__ In, const float* __restrict__ W,
    const float* __restrict__ b, float* __restrict__ Out, size_t sstride)
{
  __shared__ float As[NS][16][68]; // [stream][k][m], padded row => 16B-aligned, few conflicts
  __shared__ float Ws[16][64];     // [k][n]

  const int tid = threadIdx.x;
  const long bm = (long)blockIdx.y * 64;
  const int bn = blockIdx.x * 64;

  float acc[NS][4][4];
#pragma unroll
  for (int s = 0; s < NS; ++s)
#pragma unroll
    for (int i = 0; i < 4; ++i)
#pragma unroll
      for (int j = 0; j < 4; ++j) acc[s][i][j] = 0.f;

  const int lr = tid >> 2;          // 0..63  A-load row
  const int lc = (tid & 3) << 2;    // 0,4,8,12 A-load col (float4)
  const int wr = tid >> 4;          // 0..15  W-load row
  const int wc = (tid & 15) << 2;   // W-load col (float4)
  const int tr = (tid >> 4) << 2;   // compute row offset
  const int tc = (tid & 15) << 2;   // compute col offset

  for (int k0 = 0; k0 < HID; k0 += 16) {
    *(float4*)&Ws[wr][wc] = *(const float4*)(W + (size_t)(k0 + wr) * HID + bn + wc);
#pragma unroll
    for (int s = 0; s < NS; ++s) {
      float4 a4 = *(const float4*)(In + (size_t)s * sstride + (size_t)(bm + lr) * HID + k0 + lc);
      As[s][lc + 0][lr] = a4.x;
      As[s][lc + 1][lr] = a4.y;
      As[s][lc + 2][lr] = a4.z;
      As[s][lc + 3][lr] = a4.w;
    }
    __syncthreads();
#pragma unroll
    for (int k = 0; k < 16; ++k) {
      const float4 wv = *(const float4*)&Ws[k][tc];
#pragma unroll
      for (int s = 0; s < NS; ++s) {
        const float4 av = *(const float4*)&As[s][k][tr];
        acc[s][0][0] = fmaf(av.x, wv.x, acc[s][0][0]);
        acc[s][0][1] = fmaf(av.x, wv.y, acc[s][0][1]);
        acc[s][0][2] = fmaf(av.x, wv.z, acc[s][0][2]);
        acc[s][0][3] = fmaf(av.x, wv.w, acc[s][0][3]);
        acc[s][1][0] = fmaf(av.y, wv.x, acc[s][1][0]);
        acc[s][1][1] = fmaf(av.y, wv.y, acc[s][1][1]);
        acc[s][1][2] = fmaf(av.y, wv.z, acc[s][1][2]);
        acc[s][1][3] = fmaf(av.y, wv.w, acc[s][1][3]);
        acc[s][2][0] = fmaf(av.z, wv.x, acc[s][2][0]);
        acc[s][2][1] = fmaf(av.z, wv.y, acc[s][2][1]);
        acc[s][2][2] = fmaf(av.z, wv.z, acc[s][2][2]);
        acc[s][2][3] = fmaf(av.z, wv.w, acc[s][2][3]);
        acc[s][3][0] = fmaf(av.w, wv.x, acc[s][3][0]);
        acc[s][3][1] = fmaf(av.w, wv.y, acc[s][3][1]);
        acc[s][3][2] = fmaf(av.w, wv.z, acc[s][3][2]);
        acc[s][3][3] = fmaf(av.w, wv.w, acc[s][3][3]);
      }
    }
    __syncthreads();
  }

  // epilogue: tanh coupling, fused per (point, col)
#pragma unroll
  for (int i = 0; i < 4; ++i) {
    size_t ro = (size_t)(bm + tr + i) * HID + bn + tc;
    float o0[4], o1[4], o2[4], o3[4], o4[4];
#pragma unroll
    for (int j = 0; j < 4; ++j) {
      float a = acc[0][i][j] + b[bn + tc + j];
      float y = tanhf(a);
      float d = 1.f - y * y;
      o0[j] = y;
      float at = acc[1][i][j];
      o1[j] = d * at;
      if (NS == 5) {
        float ast = acc[2][i][j];
        float ax  = acc[3][i][j];
        float asx = acc[4][i][j];
        o2[j] = fmaf(-2.f * y * d * at, at, d * ast);
        o3[j] = d * ax;
        o4[j] = fmaf(-2.f * y * d * ax, ax, d * asx);
      }
    }
    *(float4*)(Out + ro)            = make_float4(o0[0], o0[1], o0[2], o0[3]);
    *(float4*)(Out + sstride + ro)  = make_float4(o1[0], o1[1], o1[2], o1[3]);
    if (NS == 5) {
      *(float4*)(Out + 2 * sstride + ro) = make_float4(o2[0], o2[1], o2[2], o2[3]);
      *(float4*)(Out + 3 * sstride + ro) = make_float4(o3[0], o3[1], o3[2], o3[3]);
      *(float4*)(Out + 4 * sstride + ro) = make_float4(o4[0], o4[1], o4[2], o4[3]);
    }
  }
}

// ---------------------------------------------------------------------------
// Final layer (512 -> 1) + loss accumulation. One wave per point.
// Interior: pred_f = u_tt - c^2 * u_xx; accumulate (pred_f - f)^2.
// ---------------------------------------------------------------------------
__global__ __launch_bounds__(256) void final_int_kernel(
    const float* __restrict__ act, size_t sstride,
    const float* __restrict__ W4, const float* __restrict__ f,
    const float* __restrict__ c, float* __restrict__ out,
    int rows, float scale)
{
  __shared__ float ls[4];
  int lane = threadIdx.x & 63;
  int w = threadIdx.x >> 6;
  long i = (long)blockIdx.x * 4 + w;
  float val = 0.f;
  if (i < rows) {
    const float* st = act + 2 * sstride + (size_t)i * HID;
    const float* sx = act + 4 * sstride + (size_t)i * HID;
    float s_t = 0.f, s_x = 0.f;
#pragma unroll
    for (int k = lane; k < HID; k += 64) {
      float wv = W4[k];
      s_t = fmaf(st[k], wv, s_t);
      s_x = fmaf(sx[k], wv, s_x);
    }
#pragma unroll
    for (int off = 32; off; off >>= 1) {
      s_t += __shfl_xor(s_t, off);
      s_x += __shfl_xor(s_x, off);
    }
    if (lane == 0) {
      float c0 = c[0];
      float pred = s_t - c0 * c0 * s_x;
      float r = pred - f[i];
      val = r * r;
    }
  }
  if (lane == 0) ls[w] = val;
  __syncthreads();
  if (threadIdx.x == 0) {
    atomicAdd(out + 2, scale * (ls[0] + ls[1] + ls[2] + ls[3]));
  }
}

__global__ __launch_bounds__(256) void final_init_kernel(
    const float* __restrict__ act, size_t sstride,
    const float* __restrict__ W4, const float* __restrict__ b4,
    const float* __restrict__ g, const float* __restrict__ gd,
    float* __restrict__ out, int rows, float scale)
{
  __shared__ float ls0[4], ls1[4];
  int lane = threadIdx.x & 63;
  int w = threadIdx.x >> 6;
  long i = (long)blockIdx.x * 4 + w;
  float v0 = 0.f, v1 = 0.f;
  if (i < rows) {
    const float* h  = act + (size_t)i * HID;
    const float* tt = act + sstride + (size_t)i * HID;
    float su = 0.f, stt = 0.f;
#pragma unroll
    for (int k = lane; k < HID; k += 64) {
      float wv = W4[k];
      su  = fmaf(h[k], wv, su);
      stt = fmaf(tt[k], wv, stt);
    }
#pragma unroll
    for (int off = 32; off; off >>= 1) {
      su  += __shfl_xor(su, off);
      stt += __shfl_xor(stt, off);
    }
    if (lane == 0) {
      float r0 = su + b4[0] - g[i];
      float r1 = stt - gd[i];
      v0 = r0 * r0;
      v1 = r1 * r1;
    }
  }
  if (lane == 0) { ls0[w] = v0; ls1[w] = v1; }
  __syncthreads();
  if (threadIdx.x == 0) {
    atomicAdd(out + 0, scale * (ls0[0] + ls0[1] + ls0[2] + ls0[3]));
    atomicAdd(out + 1, scale * (ls1[0] + ls1[1] + ls1[2] + ls1[3]));
  }
}

// ---------------------------------------------------------------------------
extern "C" void kernel_launch(void* const* d_in, const int* in_sizes, int n_in,
                              void* d_out, int out_size, void* d_ws, size_t ws_size,
                              hipStream_t stream)
{
  const float* xt_int  = (const float*)d_in[0];
  const float* f       = (const float*)d_in[1];
  const float* xt_init = (const float*)d_in[2];
  const float* g       = (const float*)d_in[3];
  const float* gd      = (const float*)d_in[4];
  const float* W0 = (const float*)d_in[5];
  const float* b0 = (const float*)d_in[6];
  const float* W1 = (const float*)d_in[7];
  const float* b1 = (const float*)d_in[8];
  const float* W2 = (const float*)d_in[9];
  const float* b2 = (const float*)d_in[10];
  const float* W3 = (const float*)d_in[11];
  const float* b3 = (const float*)d_in[12];
  const float* W4 = (const float*)d_in[13];
  const float* b4 = (const float*)d_in[14];
  const float* c  = (const float*)d_in[15];
  float* out = (float*)d_out;

  hipMemsetAsync(out, 0, 3 * sizeof(float), stream);

  // chunk rows so that 2 ping-pong buffers of 5 streams fit in workspace;
  // cap at 8192 so the working set (~168 MB) stays LLC-resident.
  long Rc = (long)(ws_size / (2ull * 5ull * HID * sizeof(float)));
  Rc = (Rc / 64) * 64;
  if (Rc > 8192) Rc = 8192;
  if (Rc < 64) Rc = 64;
  size_t sstride = (size_t)Rc * HID;
  float* bufA = (float*)d_ws;
  float* bufB = bufA + 5 * sstride;

  const float sc_f = 0.5f / (float)N_INT;
  const float sc_i = 0.5f / (float)N_INIT;

  // ---- interior pass (5 streams) ----
  for (long i0 = 0; i0 < N_INT; i0 += Rc) {
    long rem = N_INT - i0;
    int rows = (int)(rem < Rc ? rem : Rc);
    layer0_int_kernel<<<rows, HID, 0, stream>>>(xt_int, i0, rows, W0, b0, bufA, sstride);
    dim3 gg(HID / 64, rows / 64);
    gemm_fused<5><<<gg, 256, 0, stream>>>(bufA, W1, b1, bufB, sstride);
    gemm_fused<5><<<gg, 256, 0, stream>>>(bufB, W2, b2, bufA, sstride);
    gemm_fused<5><<<gg, 256, 0, stream>>>(bufA, W3, b3, bufB, sstride);
    final_int_kernel<<<(rows + 3) / 4, 256, 0, stream>>>(bufB, sstride, W4, f + i0, c, out, rows, sc_f);
  }

  // ---- init pass (2 streams) ----
  for (long i0 = 0; i0 < N_INIT; i0 += Rc) {
    long rem = N_INIT - i0;
    int rows = (int)(rem < Rc ? rem : Rc);
    layer0_init_kernel<<<rows, HID, 0, stream>>>(xt_init, i0, rows, W0, b0, bufA, sstride);
    dim3 gg(HID / 64, rows / 64);
    gemm_fused<2><<<gg, 256, 0, stream>>>(bufA, W1, b1, bufB, sstride);
    gemm_fused<2><<<gg, 256, 0, stream>>>(bufB, W2, b2, bufA, sstride);
    gemm_fused<2><<<gg, 256, 0, stream>>>(bufA, W3, b3, bufB, sstride);
    final_init_kernel<<<(rows + 3) / 4, 256, 0, stream>>>(bufB, sstride, W4, b4, g + i0, gd + i0, out, rows, sc_i);
  }
}

// Round 2
// 5608.300 us; speedup vs baseline: 2.6603x; 2.6603x over previous
//
#include <hip/hip_runtime.h>
#include <hip/hip_bf16.h>
#include <cstdint>
#include <cstddef>

#define HID 512
#define N_INT 131072
#define N_INIT 32768

typedef __attribute__((ext_vector_type(8))) short short8_t;
typedef __attribute__((ext_vector_type(4))) float floatx4;

__device__ __forceinline__ float bf2f(unsigned short u) {
  return __uint_as_float(((unsigned)u) << 16);
}
__device__ __forceinline__ unsigned short f2bf_rne(float x) {
  unsigned u = __float_as_uint(x);
  unsigned r = u + 0x7FFF + ((u >> 16) & 1);
  return (unsigned short)(r >> 16);
}
__device__ __forceinline__ void st_split(unsigned short* hi, unsigned short* lo,
                                         size_t off, float x) {
  unsigned short h = f2bf_rne(x);
  hi[off] = h;
  lo[off] = f2bf_rne(x - bf2f(h));
}
__device__ __forceinline__ void gl_lds16(const unsigned short* g, unsigned short* l) {
  __builtin_amdgcn_global_load_lds(
      (const __attribute__((address_space(1))) unsigned int*)g,
      (__attribute__((address_space(3))) unsigned int*)l, 16, 0, 0);
}

// ---------------------------------------------------------------------------
// Layer 0 (2 -> 512), closed-form tangents; writes bf16 hi/lo planes.
// plane index sp = stream*2 + part. interior streams: 0=h,1=u_t',2=u_tt'',3=u_x',4=u_xx''
// ---------------------------------------------------------------------------
__global__ __launch_bounds__(512) void layer0_int(
    const float* __restrict__ xt, long row0, int rows,
    const float* __restrict__ W0, const float* __restrict__ b0,
    unsigned short* __restrict__ act, size_t P)
{
  long i = blockIdx.x;
  if (i >= rows) return;
  int j = threadIdx.x;
  float x = xt[(row0 + i) * 2 + 0];
  float t = xt[(row0 + i) * 2 + 1];
  float wx = W0[j];
  float wt = W0[HID + j];
  float a = fmaf(x, wx, fmaf(t, wt, b0[j]));
  float y = tanhf(a);
  float d = 1.f - y * y;
  size_t o = ((size_t)i << 9) + j;
  st_split(act + 0 * P, act + 1 * P, o, y);
  st_split(act + 2 * P, act + 3 * P, o, d * wt);
  st_split(act + 4 * P, act + 5 * P, o, -2.f * y * d * wt * wt);
  st_split(act + 6 * P, act + 7 * P, o, d * wx);
  st_split(act + 8 * P, act + 9 * P, o, -2.f * y * d * wx * wx);
}

__global__ __launch_bounds__(512) void layer0_init(
    const float* __restrict__ xt, long row0, int rows,
    const float* __restrict__ W0, const float* __restrict__ b0,
    unsigned short* __restrict__ act, size_t P)
{
  long i = blockIdx.x;
  if (i >= rows) return;
  int j = threadIdx.x;
  float x = xt[(row0 + i) * 2 + 0];
  float t = xt[(row0 + i) * 2 + 1];
  float wx = W0[j];
  float wt = W0[HID + j];
  float a = fmaf(x, wx, fmaf(t, wt, b0[j]));
  float y = tanhf(a);
  float d = 1.f - y * y;
  size_t o = ((size_t)i << 9) + j;
  st_split(act + 0 * P, act + 1 * P, o, y);
  st_split(act + 2 * P, act + 3 * P, o, d * wt);
}

// ---------------------------------------------------------------------------
// W split + transpose: Wt[n][k] = split(W[k][n]) as bf16 hi/lo.
// ---------------------------------------------------------------------------
__global__ __launch_bounds__(512) void wsplit(
    const float* __restrict__ W,
    unsigned short* __restrict__ WtH, unsigned short* __restrict__ WtL)
{
  int n = blockIdx.x;
  int k = threadIdx.x;
  float w = W[(size_t)k * HID + n];
  size_t o = (size_t)n * HID + k;
  st_split(WtH, WtL, o, w);
}

// ---------------------------------------------------------------------------
// Fused 5(or 2)-stream split-bf16 MFMA GEMM + tanh-coupling epilogue.
// 512 thr = 8 waves (2m x 4n); block tile 64x128; wave tile 32x32 per stream.
// C = Ah@Wh + Ah@Wl + Al@Wh  (fp32 accum), per stream, shared W.
// ---------------------------------------------------------------------------
template <int NS>
__global__ __launch_bounds__(512, 2) void gemm_mfma(
    const unsigned short* __restrict__ inp,   // 2*NS planes of P elems
    const unsigned short* __restrict__ WtH,   // [512][512] (n-major)
    const unsigned short* __restrict__ WtL,
    const float* __restrict__ bias,
    unsigned short* __restrict__ outp,        // 2*NS planes
    size_t P, int nwg)
{
  __shared__ unsigned short Asm[NS * 2][64][32];
  __shared__ unsigned short Bsm[2][128][32];

  const int bid = blockIdx.x;
  // XCD-grouped order: consecutive logical blocks land on the same XCD,
  // and the 4 n-blocks of an m-panel are consecutive -> A re-reads hit L2.
  const int o = (bid & 7) * (nwg >> 3) + (bid >> 3);
  const int panel = o >> 2;
  const int nb = o & 3;
  const long bm = (long)panel << 6;
  const int bn = nb << 7;

  const int tid = threadIdx.x;
  const int lane = tid & 63;
  const int wv = tid >> 6;
  const int wm = wv & 1;
  const int wn = wv >> 1;

  floatx4 acc[NS][2][2];
#pragma unroll
  for (int s = 0; s < NS; ++s)
#pragma unroll
    for (int a = 0; a < 2; ++a)
#pragma unroll
      for (int b2 = 0; b2 < 2; ++b2)
#pragma unroll
        for (int e = 0; e < 4; ++e) acc[s][a][b2][e] = 0.f;

  const int srow = lane >> 2;        // 0..15 (staging row within 16-row slab)
  const int scol = (lane & 3) << 3;  // 0,8,16,24 ushorts = 16B slot

  constexpr int nA = NS * 2 * 4;     // A staging instrs (4 per [64][32] tile)
  constexpr int nT = nA + 16;        // + B staging instrs

  const int frow = lane & 15;
  const int fcol = (lane >> 4) << 3; // k-offset (ushorts) of this lane's frag

  for (int k0 = 0; k0 < HID; k0 += 32) {
#pragma unroll
    for (int ii = 0; ii < nT / 8; ++ii) {
      const int i = ii * 8 + wv;
      if (i < nA) {
        const int sp = i >> 2, q = i & 3;
        const unsigned short* src = inp + (size_t)sp * P +
            ((size_t)(bm + q * 16 + srow) << 9) + k0 + scol;
        gl_lds16(src, &Asm[sp][q * 16][0]);
      } else {
        const int jj = i - nA;
        const int p = jj >> 3, q = jj & 7;
        const unsigned short* src = (p ? WtL : WtH) +
            ((size_t)(bn + q * 16 + srow) << 9) + k0 + scol;
        gl_lds16(src, &Bsm[p][q * 16][0]);
      }
    }
    __syncthreads();

    const short8_t bh0 = *(const short8_t*)&Bsm[0][wn * 32 + frow][fcol];
    const short8_t bh1 = *(const short8_t*)&Bsm[0][wn * 32 + 16 + frow][fcol];
    const short8_t bl0 = *(const short8_t*)&Bsm[1][wn * 32 + frow][fcol];
    const short8_t bl1 = *(const short8_t*)&Bsm[1][wn * 32 + 16 + frow][fcol];
#pragma unroll
    for (int s = 0; s < NS; ++s) {
      const short8_t ah0 = *(const short8_t*)&Asm[s * 2][wm * 32 + frow][fcol];
      const short8_t ah1 = *(const short8_t*)&Asm[s * 2][wm * 32 + 16 + frow][fcol];
      const short8_t al0 = *(const short8_t*)&Asm[s * 2 + 1][wm * 32 + frow][fcol];
      const short8_t al1 = *(const short8_t*)&Asm[s * 2 + 1][wm * 32 + 16 + frow][fcol];
      acc[s][0][0] = __builtin_amdgcn_mfma_f32_16x16x32_bf16(ah0, bh0, acc[s][0][0], 0, 0, 0);
      acc[s][0][0] = __builtin_amdgcn_mfma_f32_16x16x32_bf16(ah0, bl0, acc[s][0][0], 0, 0, 0);
      acc[s][0][0] = __builtin_amdgcn_mfma_f32_16x16x32_bf16(al0, bh0, acc[s][0][0], 0, 0, 0);
      acc[s][0][1] = __builtin_amdgcn_mfma_f32_16x16x32_bf16(ah0, bh1, acc[s][0][1], 0, 0, 0);
      acc[s][0][1] = __builtin_amdgcn_mfma_f32_16x16x32_bf16(ah0, bl1, acc[s][0][1], 0, 0, 0);
      acc[s][0][1] = __builtin_amdgcn_mfma_f32_16x16x32_bf16(al0, bh1, acc[s][0][1], 0, 0, 0);
      acc[s][1][0] = __builtin_amdgcn_mfma_f32_16x16x32_bf16(ah1, bh0, acc[s][1][0], 0, 0, 0);
      acc[s][1][0] = __builtin_amdgcn_mfma_f32_16x16x32_bf16(ah1, bl0, acc[s][1][0], 0, 0, 0);
      acc[s][1][0] = __builtin_amdgcn_mfma_f32_16x16x32_bf16(al1, bh0, acc[s][1][0], 0, 0, 0);
      acc[s][1][1] = __builtin_amdgcn_mfma_f32_16x16x32_bf16(ah1, bh1, acc[s][1][1], 0, 0, 0);
      acc[s][1][1] = __builtin_amdgcn_mfma_f32_16x16x32_bf16(ah1, bl1, acc[s][1][1], 0, 0, 0);
      acc[s][1][1] = __builtin_amdgcn_mfma_f32_16x16x32_bf16(al1, bh1, acc[s][1][1], 0, 0, 0);
    }
    __syncthreads();
  }

  // epilogue: tanh coupling + bf16 hi/lo split stores
  const int crow4 = (lane >> 4) << 2;
#pragma unroll
  for (int rf = 0; rf < 2; ++rf) {
#pragma unroll
    for (int cf = 0; cf < 2; ++cf) {
      const int col = bn + wn * 32 + cf * 16 + frow;
      const float bv = bias[col];
#pragma unroll
      for (int j = 0; j < 4; ++j) {
        const size_t row = (size_t)(bm + wm * 32 + rf * 16 + crow4 + j);
        const size_t off = (row << 9) + col;
        const float a0 = acc[0][rf][cf][j] + bv;
        const float e = __expf(2.f * a0);
        const float y = 1.f - __fdividef(2.f, e + 1.f);
        const float d = 1.f - y * y;
        const float a1 = acc[1][rf][cf][j];
        const float o1 = d * a1;
        st_split(outp + 0 * P, outp + 1 * P, off, y);
        st_split(outp + 2 * P, outp + 3 * P, off, o1);
        if (NS == 5) {
          const float a2 = acc[2][rf][cf][j];
          const float a3 = acc[3][rf][cf][j];
          const float a4 = acc[4][rf][cf][j];
          const float o2 = fmaf(-2.f * y * a1, o1, d * a2);
          const float o3 = d * a3;
          const float o4 = fmaf(-2.f * y * a3, o3, d * a4);
          st_split(outp + 4 * P, outp + 5 * P, off, o2);
          st_split(outp + 6 * P, outp + 7 * P, off, o3);
          st_split(outp + 8 * P, outp + 9 * P, off, o4);
        }
      }
    }
  }
}

// ---------------------------------------------------------------------------
// Final layer (512 -> 1) dots + loss accumulation. One wave per point.
// ---------------------------------------------------------------------------
__global__ __launch_bounds__(256) void final_int(
    const unsigned short* __restrict__ act, size_t P,
    const float* __restrict__ W4, const float* __restrict__ f,
    const float* __restrict__ c, float* __restrict__ out,
    int rows, float scale)
{
  __shared__ float ls[4];
  int lane = threadIdx.x & 63, w = threadIdx.x >> 6;
  long i = (long)blockIdx.x * 4 + w;
  float val = 0.f;
  if (i < rows) {
    size_t ro = ((size_t)i << 9) + (lane << 3);
    short8_t h2 = *(const short8_t*)(act + 4 * P + ro);
    short8_t l2 = *(const short8_t*)(act + 5 * P + ro);
    short8_t h4 = *(const short8_t*)(act + 8 * P + ro);
    short8_t l4 = *(const short8_t*)(act + 9 * P + ro);
    float s_t = 0.f, s_x = 0.f;
#pragma unroll
    for (int j = 0; j < 8; ++j) {
      float wv4 = W4[(lane << 3) + j];
      s_t = fmaf(bf2f((unsigned short)h2[j]) + bf2f((unsigned short)l2[j]), wv4, s_t);
      s_x = fmaf(bf2f((unsigned short)h4[j]) + bf2f((unsigned short)l4[j]), wv4, s_x);
    }
#pragma unroll
    for (int off = 32; off; off >>= 1) {
      s_t += __shfl_xor(s_t, off);
      s_x += __shfl_xor(s_x, off);
    }
    if (lane == 0) {
      float c0 = c[0];
      float pred = s_t - c0 * c0 * s_x;
      float r = pred - f[i];
      val = r * r;
    }
  }
  if (lane == 0) ls[w] = val;
  __syncthreads();
  if (threadIdx.x == 0)
    atomicAdd(out + 2, scale * (ls[0] + ls[1] + ls[2] + ls[3]));
}

__global__ __launch_bounds__(256) void final_init(
    const unsigned short* __restrict__ act, size_t P,
    const float* __restrict__ W4, const float* __restrict__ b4,
    const float* __restrict__ g, const float* __restrict__ gd,
    float* __restrict__ out, int rows, float scale)
{
  __shared__ float ls0[4], ls1[4];
  int lane = threadIdx.x & 63, w = threadIdx.x >> 6;
  long i = (long)blockIdx.x * 4 + w;
  float v0 = 0.f, v1 = 0.f;
  if (i < rows) {
    size_t ro = ((size_t)i << 9) + (lane << 3);
    short8_t h0 = *(const short8_t*)(act + 0 * P + ro);
    short8_t l0 = *(const short8_t*)(act + 1 * P + ro);
    short8_t h1 = *(const short8_t*)(act + 2 * P + ro);
    short8_t l1 = *(const short8_t*)(act + 3 * P + ro);
    float su = 0.f, stt = 0.f;
#pragma unroll
    for (int j = 0; j < 8; ++j) {
      float wv4 = W4[(lane << 3) + j];
      su  = fmaf(bf2f((unsigned short)h0[j]) + bf2f((unsigned short)l0[j]), wv4, su);
      stt = fmaf(bf2f((unsigned short)h1[j]) + bf2f((unsigned short)l1[j]), wv4, stt);
    }
#pragma unroll
    for (int off = 32; off; off >>= 1) {
      su  += __shfl_xor(su, off);
      stt += __shfl_xor(stt, off);
    }
    if (lane == 0) {
      float r0 = su + b4[0] - g[i];
      float r1 = stt - gd[i];
      v0 = r0 * r0;
      v1 = r1 * r1;
    }
  }
  if (lane == 0) { ls0[w] = v0; ls1[w] = v1; }
  __syncthreads();
  if (threadIdx.x == 0) {
    atomicAdd(out + 0, scale * (ls0[0] + ls0[1] + ls0[2] + ls0[3]));
    atomicAdd(out + 1, scale * (ls1[0] + ls1[1] + ls1[2] + ls1[3]));
  }
}

// ---------------------------------------------------------------------------
extern "C" void kernel_launch(void* const* d_in, const int* in_sizes, int n_in,
                              void* d_out, int out_size, void* d_ws, size_t ws_size,
                              hipStream_t stream)
{
  const float* xt_int  = (const float*)d_in[0];
  const float* f       = (const float*)d_in[1];
  const float* xt_init = (const float*)d_in[2];
  const float* g       = (const float*)d_in[3];
  const float* gd      = (const float*)d_in[4];
  const float* W0 = (const float*)d_in[5];
  const float* b0 = (const float*)d_in[6];
  const float* W1 = (const float*)d_in[7];
  const float* b1 = (const float*)d_in[8];
  const float* W2 = (const float*)d_in[9];
  const float* b2 = (const float*)d_in[10];
  const float* W3 = (const float*)d_in[11];
  const float* b3 = (const float*)d_in[12];
  const float* W4 = (const float*)d_in[13];
  const float* b4 = (const float*)d_in[14];
  const float* c  = (const float*)d_in[15];
  float* out = (float*)d_out;

  hipMemsetAsync(out, 0, 3 * sizeof(float), stream);

  unsigned short* wsp = (unsigned short*)d_ws;
  const size_t WT1 = (size_t)HID * HID;     // one 512x512 plane (elems)
  const size_t wtotal = 6 * WT1;            // 3 layers x {hi,lo}
  unsigned short* Wt = wsp;

  long maxRc = (long)((ws_size / 2 - wtotal) / (20 * HID)); // rows for 2x10 planes
  long Rc = 128;
  while (Rc * 2 <= maxRc && Rc < 8192) Rc <<= 1;
  size_t P = (size_t)Rc * HID;
  unsigned short* bufA = wsp + wtotal;
  unsigned short* bufB = bufA + 10 * P;

  wsplit<<<HID, HID, 0, stream>>>(W1, Wt + 0 * WT1, Wt + 1 * WT1);
  wsplit<<<HID, HID, 0, stream>>>(W2, Wt + 2 * WT1, Wt + 3 * WT1);
  wsplit<<<HID, HID, 0, stream>>>(W3, Wt + 4 * WT1, Wt + 5 * WT1);

  const float sc_f = 0.5f / (float)N_INT;
  const float sc_i = 0.5f / (float)N_INIT;

  // ---- interior pass (5 streams) ----
  for (long i0 = 0; i0 < N_INT; i0 += Rc) {
    long rem = N_INT - i0;
    int rows = (int)(rem < Rc ? rem : Rc);
    layer0_int<<<rows, HID, 0, stream>>>(xt_int, i0, rows, W0, b0, bufA, P);
    int nwg = (rows / 64) * 4;
    gemm_mfma<5><<<nwg, 512, 0, stream>>>(bufA, Wt + 0 * WT1, Wt + 1 * WT1, b1, bufB, P, nwg);
    gemm_mfma<5><<<nwg, 512, 0, stream>>>(bufB, Wt + 2 * WT1, Wt + 3 * WT1, b2, bufA, P, nwg);
    gemm_mfma<5><<<nwg, 512, 0, stream>>>(bufA, Wt + 4 * WT1, Wt + 5 * WT1, b3, bufB, P, nwg);
    final_int<<<(rows + 3) / 4, 256, 0, stream>>>(bufB, P, W4, f + i0, c, out, rows, sc_f);
  }

  // ---- init pass (2 streams) ----
  for (long i0 = 0; i0 < N_INIT; i0 += Rc) {
    long rem = N_INIT - i0;
    int rows = (int)(rem < Rc ? rem : Rc);
    layer0_init<<<rows, HID, 0, stream>>>(xt_init, i0, rows, W0, b0, bufA, P);
    int nwg = (rows / 64) * 4;
    gemm_mfma<2><<<nwg, 512, 0, stream>>>(bufA, Wt + 0 * WT1, Wt + 1 * WT1, b1, bufB, P, nwg);
    gemm_mfma<2><<<nwg, 512, 0, stream>>>(bufB, Wt + 2 * WT1, Wt + 3 * WT1, b2, bufA, P, nwg);
    gemm_mfma<2><<<nwg, 512, 0, stream>>>(bufA, Wt + 4 * WT1, Wt + 5 * WT1, b3, bufB, P, nwg);
    final_init<<<(rows + 3) / 4, 256, 0, stream>>>(bufB, P, W4, b4, g + i0, gd + i0, out, rows, sc_i);
  }
}

// Round 3
// 5135.383 us; speedup vs baseline: 2.9052x; 1.0921x over previous
//
#include <hip/hip_runtime.h>
#include <hip/hip_bf16.h>
#include <cstdint>
#include <cstddef>

#define HID 512
#define N_INT 131072
#define N_INIT 32768

typedef __attribute__((ext_vector_type(8))) short short8_t;
typedef __attribute__((ext_vector_type(4))) float floatx4;

__device__ __forceinline__ float bf2f(unsigned short u) {
  return __uint_as_float(((unsigned)u) << 16);
}
__device__ __forceinline__ unsigned short f2bf_rne(float x) {
  unsigned u = __float_as_uint(x);
  unsigned r = u + 0x7FFF + ((u >> 16) & 1);
  return (unsigned short)(r >> 16);
}
__device__ __forceinline__ void st_split(unsigned short* hi, unsigned short* lo,
                                         size_t off, float x) {
  unsigned short h = f2bf_rne(x);
  hi[off] = h;
  lo[off] = f2bf_rne(x - bf2f(h));
}
__device__ __forceinline__ void gl_lds16(const unsigned short* g, unsigned short* l) {
  __builtin_amdgcn_global_load_lds(
      (const __attribute__((address_space(1))) unsigned int*)g,
      (__attribute__((address_space(3))) unsigned int*)l, 16, 0, 0);
}

// ---------------------------------------------------------------------------
// Layer 0 (2 -> 512), closed-form tangents; writes bf16 hi/lo planes.
// ---------------------------------------------------------------------------
__global__ __launch_bounds__(512) void layer0_int(
    const float* __restrict__ xt, long row0, int rows,
    const float* __restrict__ W0, const float* __restrict__ b0,
    unsigned short* __restrict__ act, size_t P)
{
  long i = blockIdx.x;
  if (i >= rows) return;
  int j = threadIdx.x;
  float x = xt[(row0 + i) * 2 + 0];
  float t = xt[(row0 + i) * 2 + 1];
  float wx = W0[j];
  float wt = W0[HID + j];
  float a = fmaf(x, wx, fmaf(t, wt, b0[j]));
  float y = tanhf(a);
  float d = 1.f - y * y;
  size_t o = ((size_t)i << 9) + j;
  st_split(act + 0 * P, act + 1 * P, o, y);
  st_split(act + 2 * P, act + 3 * P, o, d * wt);
  st_split(act + 4 * P, act + 5 * P, o, -2.f * y * d * wt * wt);
  st_split(act + 6 * P, act + 7 * P, o, d * wx);
  st_split(act + 8 * P, act + 9 * P, o, -2.f * y * d * wx * wx);
}

__global__ __launch_bounds__(512) void layer0_init(
    const float* __restrict__ xt, long row0, int rows,
    const float* __restrict__ W0, const float* __restrict__ b0,
    unsigned short* __restrict__ act, size_t P)
{
  long i = blockIdx.x;
  if (i >= rows) return;
  int j = threadIdx.x;
  float x = xt[(row0 + i) * 2 + 0];
  float t = xt[(row0 + i) * 2 + 1];
  float wx = W0[j];
  float wt = W0[HID + j];
  float a = fmaf(x, wx, fmaf(t, wt, b0[j]));
  float y = tanhf(a);
  float d = 1.f - y * y;
  size_t o = ((size_t)i << 9) + j;
  st_split(act + 0 * P, act + 1 * P, o, y);
  st_split(act + 2 * P, act + 3 * P, o, d * wt);
}

// ---------------------------------------------------------------------------
// W split + transpose: Wt[n][k] = split(W[k][n]) as bf16 hi/lo.
// ---------------------------------------------------------------------------
__global__ __launch_bounds__(512) void wsplit(
    const float* __restrict__ W,
    unsigned short* __restrict__ WtH, unsigned short* __restrict__ WtL)
{
  int n = blockIdx.x;
  int k = threadIdx.x;
  float w = W[(size_t)k * HID + n];
  size_t o = (size_t)n * HID + k;
  st_split(WtH, WtL, o, w);
}

// ---------------------------------------------------------------------------
// Fused NS-stream split-bf16 MFMA GEMM + tanh-coupling epilogue.
// 256 thr = 4 waves (2m x 2n); block tile 64x128; wave tile 32x64 per stream.
// LDS rows are 128B: [hi q0..q3 | lo q0..q3], 16B slot phys = logical ^ (row&7)
// (conflict-free ds_read_b128; global_load_lds dest linear, SOURCE pre-swizzled).
// C = Ah@Wh + Ah@Wl + Al@Wh  (fp32 accum), per stream, shared W.
// ---------------------------------------------------------------------------
template <int NS>
__global__ __launch_bounds__(256, 2) void gemm_mfma(
    const unsigned short* __restrict__ inp,   // 2*NS planes of P elems
    const unsigned short* __restrict__ WtH,   // [512][512] (n-major)
    const unsigned short* __restrict__ WtL,
    const float* __restrict__ bias,
    unsigned short* __restrict__ outp,        // 2*NS planes
    size_t P, int nwg)
{
  __shared__ unsigned short Asm[NS][64][64];  // per stream: 64 rows x (hi32|lo32)
  __shared__ unsigned short Bsm[128][64];     // 128 cols   x (hi32|lo32)

  const int bid = blockIdx.x;
  // XCD-grouped order (nwg always multiple of 8 here): consecutive logical
  // blocks share an XCD; 4 n-blocks of an m-panel are consecutive -> A in L2.
  const int o = (bid & 7) * (nwg >> 3) + (bid >> 3);
  const long bm = (long)(o >> 2) << 6;
  const int bn = (o & 3) << 7;

  const int tid = threadIdx.x;
  const int lane = tid & 63;
  const int wv = tid >> 6;   // 0..3
  const int wm = wv & 1;     // 32-row half
  const int wn = wv >> 1;    // 64-col half

  floatx4 acc[NS][2][4];
#pragma unroll
  for (int s = 0; s < NS; ++s)
#pragma unroll
    for (int a = 0; a < 2; ++a)
#pragma unroll
      for (int b2 = 0; b2 < 4; ++b2)
#pragma unroll
        for (int e = 0; e < 4; ++e) acc[s][a][b2][e] = 0.f;

  // ---- staging decomposition: one gl_lds = 1024B = 8 rows of 128B.
  // dest lane l -> row (l>>3), phys slot (l&7); logical slot = (l&7)^(l>>3).
  const int srow = lane >> 3;
  const int sl = (lane & 7) ^ srow;   // logical slot
  const int sp = sl >> 2;             // 0=hi plane, 1=lo plane
  const int sq = sl & 3;              // k-quarter (8 ushorts)
  const size_t s_lane = ((size_t)srow << 9) + (size_t)(sq << 3);

  const unsigned short* bsrc = (sp ? WtL : WtH) + ((size_t)bn << 9) + s_lane;
  const unsigned short* asrc[NS];
#pragma unroll
  for (int s = 0; s < NS; ++s)
    asrc[s] = inp + (size_t)(2 * s + sp) * P + ((size_t)bm << 9) + s_lane;

  // ---- fragment-read decomposition
  const int frow = lane & 15;
  const int fq = lane >> 4;                 // k-quarter
  const int ph = fq ^ (lane & 7);           // physical slot, hi
  const int pl = ph ^ 4;                    // physical slot, lo
  const int ab = (wm * 32 + frow) * 64;     // A frag0 row base (ushorts)
  const int bb0 = (wn * 64 + frow) * 64;    // B cf=0 row base

  for (int k0 = 0; k0 < HID; k0 += 32) {
    // ---- stage next tile (wave wv: 2 A-slabs per stream + 4 B-slabs)
#pragma unroll
    for (int s = 0; s < NS; ++s)
#pragma unroll
      for (int u = 0; u < 2; ++u) {
        const int sub = wv * 2 + u;  // 8-row slab
        gl_lds16(asrc[s] + ((size_t)sub << 12) + k0, &Asm[s][sub << 3][0]);
      }
#pragma unroll
    for (int u = 0; u < 4; ++u) {
      const int j = wv * 4 + u;
      gl_lds16(bsrc + ((size_t)j << 12) + k0, &Bsm[j << 3][0]);
    }
    __syncthreads();

    // ---- B fragments (shared across streams)
    short8_t bh[4], bl[4];
#pragma unroll
    for (int cf = 0; cf < 4; ++cf) {
      const unsigned short* Bp = &Bsm[0][0] + bb0 + cf * (16 * 64);
      bh[cf] = *(const short8_t*)(Bp + ph * 8);
      bl[cf] = *(const short8_t*)(Bp + pl * 8);
    }
#pragma unroll
    for (int s = 0; s < NS; ++s) {
      const unsigned short* As = &Asm[s][0][0];
      const short8_t ah0 = *(const short8_t*)(As + ab + ph * 8);
      const short8_t al0 = *(const short8_t*)(As + ab + pl * 8);
      const short8_t ah1 = *(const short8_t*)(As + ab + 1024 + ph * 8);
      const short8_t al1 = *(const short8_t*)(As + ab + 1024 + pl * 8);
#pragma unroll
      for (int cf = 0; cf < 4; ++cf) {
        acc[s][0][cf] = __builtin_amdgcn_mfma_f32_16x16x32_bf16(ah0, bh[cf], acc[s][0][cf], 0, 0, 0);
        acc[s][0][cf] = __builtin_amdgcn_mfma_f32_16x16x32_bf16(ah0, bl[cf], acc[s][0][cf], 0, 0, 0);
        acc[s][0][cf] = __builtin_amdgcn_mfma_f32_16x16x32_bf16(al0, bh[cf], acc[s][0][cf], 0, 0, 0);
        acc[s][1][cf] = __builtin_amdgcn_mfma_f32_16x16x32_bf16(ah1, bh[cf], acc[s][1][cf], 0, 0, 0);
        acc[s][1][cf] = __builtin_amdgcn_mfma_f32_16x16x32_bf16(ah1, bl[cf], acc[s][1][cf], 0, 0, 0);
        acc[s][1][cf] = __builtin_amdgcn_mfma_f32_16x16x32_bf16(al1, bh[cf], acc[s][1][cf], 0, 0, 0);
      }
    }
    __syncthreads();
  }

  // ---- epilogue: tanh coupling + bf16 hi/lo split stores
  const int crow4 = fq << 2;
#pragma unroll
  for (int rf = 0; rf < 2; ++rf) {
#pragma unroll
    for (int cf = 0; cf < 4; ++cf) {
      const int col = bn + wn * 64 + cf * 16 + frow;
      const float bv = bias[col];
#pragma unroll
      for (int j = 0; j < 4; ++j) {
        const size_t row = (size_t)(bm + wm * 32 + rf * 16 + crow4 + j);
        const size_t off = (row << 9) + col;
        const float a0 = acc[0][rf][cf][j] + bv;
        const float e = __expf(2.f * a0);
        const float y = 1.f - __fdividef(2.f, e + 1.f);
        const float d = 1.f - y * y;
        const float a1 = acc[1][rf][cf][j];
        const float o1 = d * a1;
        st_split(outp + 0 * P, outp + 1 * P, off, y);
        st_split(outp + 2 * P, outp + 3 * P, off, o1);
        if (NS == 5) {
          const float a2 = acc[2][rf][cf][j];
          const float a3 = acc[3][rf][cf][j];
          const float a4 = acc[4][rf][cf][j];
          const float o2 = fmaf(-2.f * y * a1, o1, d * a2);
          const float o3 = d * a3;
          const float o4 = fmaf(-2.f * y * a3, o3, d * a4);
          st_split(outp + 4 * P, outp + 5 * P, off, o2);
          st_split(outp + 6 * P, outp + 7 * P, off, o3);
          st_split(outp + 8 * P, outp + 9 * P, off, o4);
        }
      }
    }
  }
}

// ---------------------------------------------------------------------------
// Final layer (512 -> 1) dots + loss accumulation. One wave per point.
// ---------------------------------------------------------------------------
__global__ __launch_bounds__(256) void final_int(
    const unsigned short* __restrict__ act, size_t P,
    const float* __restrict__ W4, const float* __restrict__ f,
    const float* __restrict__ c, float* __restrict__ out,
    int rows, float scale)
{
  __shared__ float ls[4];
  int lane = threadIdx.x & 63, w = threadIdx.x >> 6;
  long i = (long)blockIdx.x * 4 + w;
  float val = 0.f;
  if (i < rows) {
    size_t ro = ((size_t)i << 9) + (lane << 3);
    short8_t h2 = *(const short8_t*)(act + 4 * P + ro);
    short8_t l2 = *(const short8_t*)(act + 5 * P + ro);
    short8_t h4 = *(const short8_t*)(act + 8 * P + ro);
    short8_t l4 = *(const short8_t*)(act + 9 * P + ro);
    float s_t = 0.f, s_x = 0.f;
#pragma unroll
    for (int j = 0; j < 8; ++j) {
      float wv4 = W4[(lane << 3) + j];
      s_t = fmaf(bf2f((unsigned short)h2[j]) + bf2f((unsigned short)l2[j]), wv4, s_t);
      s_x = fmaf(bf2f((unsigned short)h4[j]) + bf2f((unsigned short)l4[j]), wv4, s_x);
    }
#pragma unroll
    for (int off = 32; off; off >>= 1) {
      s_t += __shfl_xor(s_t, off);
      s_x += __shfl_xor(s_x, off);
    }
    if (lane == 0) {
      float c0 = c[0];
      float pred = s_t - c0 * c0 * s_x;
      float r = pred - f[i];
      val = r * r;
    }
  }
  if (lane == 0) ls[w] = val;
  __syncthreads();
  if (threadIdx.x == 0)
    atomicAdd(out + 2, scale * (ls[0] + ls[1] + ls[2] + ls[3]));
}

__global__ __launch_bounds__(256) void final_init(
    const unsigned short* __restrict__ act, size_t P,
    const float* __restrict__ W4, const float* __restrict__ b4,
    const float* __restrict__ g, const float* __restrict__ gd,
    float* __restrict__ out, int rows, float scale)
{
  __shared__ float ls0[4], ls1[4];
  int lane = threadIdx.x & 63, w = threadIdx.x >> 6;
  long i = (long)blockIdx.x * 4 + w;
  float v0 = 0.f, v1 = 0.f;
  if (i < rows) {
    size_t ro = ((size_t)i << 9) + (lane << 3);
    short8_t h0 = *(const short8_t*)(act + 0 * P + ro);
    short8_t l0 = *(const short8_t*)(act + 1 * P + ro);
    short8_t h1 = *(const short8_t*)(act + 2 * P + ro);
    short8_t l1 = *(const short8_t*)(act + 3 * P + ro);
    float su = 0.f, stt = 0.f;
#pragma unroll
    for (int j = 0; j < 8; ++j) {
      float wv4 = W4[(lane << 3) + j];
      su  = fmaf(bf2f((unsigned short)h0[j]) + bf2f((unsigned short)l0[j]), wv4, su);
      stt = fmaf(bf2f((unsigned short)h1[j]) + bf2f((unsigned short)l1[j]), wv4, stt);
    }
#pragma unroll
    for (int off = 32; off; off >>= 1) {
      su  += __shfl_xor(su, off);
      stt += __shfl_xor(stt, off);
    }
    if (lane == 0) {
      float r0 = su + b4[0] - g[i];
      float r1 = stt - gd[i];
      v0 = r0 * r0;
      v1 = r1 * r1;
    }
  }
  if (lane == 0) { ls0[w] = v0; ls1[w] = v1; }
  __syncthreads();
  if (threadIdx.x == 0) {
    atomicAdd(out + 0, scale * (ls0[0] + ls0[1] + ls0[2] + ls0[3]));
    atomicAdd(out + 1, scale * (ls1[0] + ls1[1] + ls1[2] + ls1[3]));
  }
}

// ---------------------------------------------------------------------------
extern "C" void kernel_launch(void* const* d_in, const int* in_sizes, int n_in,
                              void* d_out, int out_size, void* d_ws, size_t ws_size,
                              hipStream_t stream)
{
  const float* xt_int  = (const float*)d_in[0];
  const float* f       = (const float*)d_in[1];
  const float* xt_init = (const float*)d_in[2];
  const float* g       = (const float*)d_in[3];
  const float* gd      = (const float*)d_in[4];
  const float* W0 = (const float*)d_in[5];
  const float* b0 = (const float*)d_in[6];
  const float* W1 = (const float*)d_in[7];
  const float* b1 = (const float*)d_in[8];
  const float* W2 = (const float*)d_in[9];
  const float* b2 = (const float*)d_in[10];
  const float* W3 = (const float*)d_in[11];
  const float* b3 = (const float*)d_in[12];
  const float* W4 = (const float*)d_in[13];
  const float* b4 = (const float*)d_in[14];
  const float* c  = (const float*)d_in[15];
  float* out = (float*)d_out;

  hipMemsetAsync(out, 0, 3 * sizeof(float), stream);

  unsigned short* wsp = (unsigned short*)d_ws;
  const size_t WT1 = (size_t)HID * HID;     // one 512x512 plane (elems)
  const size_t wtotal = 6 * WT1;            // 3 layers x {hi,lo}
  unsigned short* Wt = wsp;

  long maxRc = (long)((ws_size / 2 - wtotal) / (20 * HID)); // rows for 2x10 planes
  long Rc = 128;
  while (Rc * 2 <= maxRc && Rc < 8192) Rc <<= 1;
  size_t P = (size_t)Rc * HID;
  unsigned short* bufA = wsp + wtotal;
  unsigned short* bufB = bufA + 10 * P;

  wsplit<<<HID, HID, 0, stream>>>(W1, Wt + 0 * WT1, Wt + 1 * WT1);
  wsplit<<<HID, HID, 0, stream>>>(W2, Wt + 2 * WT1, Wt + 3 * WT1);
  wsplit<<<HID, HID, 0, stream>>>(W3, Wt + 4 * WT1, Wt + 5 * WT1);

  const float sc_f = 0.5f / (float)N_INT;
  const float sc_i = 0.5f / (float)N_INIT;

  // ---- interior pass (5 streams) ----
  for (long i0 = 0; i0 < N_INT; i0 += Rc) {
    long rem = N_INT - i0;
    int rows = (int)(rem < Rc ? rem : Rc);
    layer0_int<<<rows, HID, 0, stream>>>(xt_int, i0, rows, W0, b0, bufA, P);
    int nwg = (rows / 64) * 4;
    gemm_mfma<5><<<nwg, 256, 0, stream>>>(bufA, Wt + 0 * WT1, Wt + 1 * WT1, b1, bufB, P, nwg);
    gemm_mfma<5><<<nwg, 256, 0, stream>>>(bufB, Wt + 2 * WT1, Wt + 3 * WT1, b2, bufA, P, nwg);
    gemm_mfma<5><<<nwg, 256, 0, stream>>>(bufA, Wt + 4 * WT1, Wt + 5 * WT1, b3, bufB, P, nwg);
    final_int<<<(rows + 3) / 4, 256, 0, stream>>>(bufB, P, W4, f + i0, c, out, rows, sc_f);
  }

  // ---- init pass (2 streams) ----
  for (long i0 = 0; i0 < N_INIT; i0 += Rc) {
    long rem = N_INIT - i0;
    int rows = (int)(rem < Rc ? rem : Rc);
    layer0_init<<<rows, HID, 0, stream>>>(xt_init, i0, rows, W0, b0, bufA, P);
    int nwg = (rows / 64) * 4;
    gemm_mfma<2><<<nwg, 256, 0, stream>>>(bufA, Wt + 0 * WT1, Wt + 1 * WT1, b1, bufB, P, nwg);
    gemm_mfma<2><<<nwg, 256, 0, stream>>>(bufB, Wt + 2 * WT1, Wt + 3 * WT1, b2, bufA, P, nwg);
    gemm_mfma<2><<<nwg, 256, 0, stream>>>(bufA, Wt + 4 * WT1, Wt + 5 * WT1, b3, bufB, P, nwg);
    final_init<<<(rows + 3) / 4, 256, 0, stream>>>(bufB, P, W4, b4, g + i0, gd + i0, out, rows, sc_i);
  }
}